// Round 1
// baseline (82.290 us; speedup 1.0000x reference)
//
#include <hip/hip_runtime.h>
#include <math.h>

namespace {

constexpr int LDSS = 76;        // float stride per (channel,blk) 8x8 region: 64 data + 12 pad (2-way banks max)
constexpr int CSTR = 8 * LDSS;  // 608 floats per channel span (block regions and row-layout overlay share it)

// DCT matrix as compile-time constants so the unrolled FMAs use hoisted literals.
struct DctMat {
  float d[8][8];
  constexpr DctMat() : d{} {
    const float CT[17] = {
        1.0f, 0.9807852804032304f, 0.9238795325112867f, 0.8314696123025452f,
        0.7071067811865476f, 0.5555702330196022f, 0.3826834323650898f,
        0.19509032201612825f, 0.0f, -0.19509032201612825f,
        -0.3826834323650898f, -0.5555702330196022f, -0.7071067811865476f,
        -0.8314696123025452f, -0.9238795325112867f, -0.9807852804032304f,
        -1.0f};
    for (int i = 0; i < 8; ++i)
      for (int j = 0; j < 8; ++j) {
        if (i == 0) {
          d[i][j] = 0.35355339059327373f;  // sqrt(1/8)
        } else {
          int m = ((2 * j + 1) * i) % 32;
          if (m > 16) m = 32 - m;
          d[i][j] = 0.5f * CT[m];
        }
      }
  }
};
constexpr DctMat DM{};

// t[i] = sum_j a[j] * D[i][j]   (TRANSPOSED=false)
// t[i] = sum_j a[j] * D[j][i]   (TRANSPOSED=true)
template <bool TRANSPOSED>
__device__ __forceinline__ void mul8(const float (&a)[8], float (&t)[8]) {
#pragma unroll
  for (int i = 0; i < 8; ++i) {
    float s = 0.0f;
#pragma unroll
    for (int j = 0; j < 8; ++j) {
      s = fmaf(a[j], TRANSPOSED ? DM.d[j][i] : DM.d[i][j], s);
    }
    t[i] = s;
  }
}

__device__ __forceinline__ void load8(const float* __restrict__ p, float (&a)[8]) {
  float4 v0 = *reinterpret_cast<const float4*>(p);
  float4 v1 = *reinterpret_cast<const float4*>(p + 4);
  a[0] = v0.x; a[1] = v0.y; a[2] = v0.z; a[3] = v0.w;
  a[4] = v1.x; a[5] = v1.y; a[6] = v1.z; a[7] = v1.w;
}

__device__ __forceinline__ void store8(float* __restrict__ p, const float (&a)[8]) {
  float4 v0 = {a[0], a[1], a[2], a[3]};
  float4 v1 = {a[4], a[5], a[6], a[7]};
  *reinterpret_cast<float4*>(p) = v0;
  *reinterpret_cast<float4*>(p + 4) = v1;
}

__device__ __forceinline__ void load8_lds(const float* p, float (&a)[8]) {
  float4 v0 = *reinterpret_cast<const float4*>(p);
  float4 v1 = *reinterpret_cast<const float4*>(p + 4);
  a[0] = v0.x; a[1] = v0.y; a[2] = v0.z; a[3] = v0.w;
  a[4] = v1.x; a[5] = v1.y; a[6] = v1.z; a[7] = v1.w;
}

__device__ __forceinline__ void store8_lds(float* p, const float (&a)[8]) {
  float4 v0 = {a[0], a[1], a[2], a[3]};
  float4 v1 = {a[4], a[5], a[6], a[7]};
  *reinterpret_cast<float4*>(p) = v0;
  *reinterpret_cast<float4*>(p + 4) = v1;
}

// Single-channel 8x8 transpose across the 8 lanes sharing each block.
// All 8 lanes of a block live in the SAME wave, so a wave-local lgkmcnt(0)
// drain (not a workgroup barrier) is the correct RAW fence — this keeps the
// 3 channel-waves of the workgroup fully decoupled here.
// WAR on region reuse is safe: every later ds_write's data depends on the
// ds_read results, so reads have retired before the writes can issue.
__device__ __forceinline__ void transpose1(float (&T)[8], float* lp, int r) {
#pragma unroll
  for (int j = 0; j < 8; ++j) lp[j * 8 + r] = T[j];  // scatter-write transposed
  asm volatile("s_waitcnt lgkmcnt(0)" ::: "memory");
  __builtin_amdgcn_sched_barrier(0);  // rule #18: pin consumers behind the wait
  const float* rp = lp + r * 8;
  float4 v0 = *reinterpret_cast<const float4*>(rp);      // ds_read_b128
  float4 v1 = *reinterpret_cast<const float4*>(rp + 4);  // ds_read_b128
  T[0] = v0.x; T[1] = v0.y; T[2] = v0.z; T[3] = v0.w;
  T[4] = v1.x; T[5] = v1.y; T[6] = v1.z; T[7] = v1.w;
}

// Soft-round quantization. soft_round(x) ~= kc + sigmoid(50*(x-kc-0.5)),
// kc = floor(x); the [-10,9] clamp of the reference is provably never active:
// |coef| <= (sum_j|D_ij|)^2 <= 8 and q >= 2  =>  |x| <= 4, floor(x) in [-5,4].
// Reciprocals of q are hoisted to the prologue (1 trans op saved per element).
__device__ __forceinline__ void quant8(float (&a)[8], const float (&q)[8],
                                       const float (&rq)[8]) {
#pragma unroll
  for (int i = 0; i < 8; ++i) {
    float x = a[i] * rq[i];
    float kc = floorf(x);
    float arg = 50.0f * (x - kc - 0.5f);
    float e = __expf(-arg);
    float sr = kc + __builtin_amdgcn_rcpf(1.0f + e);
    a[i] = sr * q[i];
  }
}

// 3 waves per workgroup, one channel per wave. Wave c loads/stores only
// channel c; color conversions exchange channels through LDS row-layout
// staging (2 barriers fwd + 1 back). The DCT/quant/iDCT core is per-wave
// independent -> 12288 total waves (~30 resident/CU) vs 4096 before.
__global__ __launch_bounds__(192) void jpeg_kernel(
    const float* __restrict__ img, const float* __restrict__ qy,
    const float* __restrict__ qc, float* __restrict__ out) {
  __shared__ float lds[3 * CSTR];  // 7.3 KB per workgroup

  const int c = __builtin_amdgcn_readfirstlane(threadIdx.x >> 6);  // wave = channel
  const int lane = threadIdx.x & 63;
  const int blk = lane & 7;  // which of the strip's 8 blocks
  const int r = lane >> 3;   // row within the block

  const int w = blockIdx.x;  // strip id, 0..4095
  const int b = w >> 9;      // batch (512 strips per batch)
  const int rr = w & 511;
  const int u = rr >> 3;         // block-row, 0..63
  const int v0 = (rr & 7) << 3;  // first block-col of this strip

  const int row = u * 8 + r;
  const int col = (v0 + blk) * 8;

  const size_t ims = 512 * 512;
  const size_t poff = ((size_t)b * 3 + c) * ims + (size_t)row * 512 + col;

  // Issue own-channel image loads first, q-table loads right behind.
  float X[8];
  load8(img + poff, X);

  const float* qt = (c == 0) ? qy : qc;
  float qcol[8], rqcol[8];
#pragma unroll
  for (int i = 0; i < 8; ++i) {
    float qv = fminf(fmaxf(qt[i * 8 + r], 2.0f), 15.0f);
    qcol[i] = qv;
    rqcol[i] = __builtin_amdgcn_rcpf(qv);
  }

  // Clip and stage own channel in row layout: lds[c*CSTR + r*LDSS + col].
#pragma unroll
  for (int i = 0; i < 8; ++i) X[i] = fminf(fmaxf(X[i], 0.0f), 1.0f);
  float* sp = lds + c * CSTR + r * LDSS + blk * 8;
  store8_lds(sp, X);
  __syncthreads();  // Bar1: all channels staged

  // RGB -> own YCbCr component (each wave reads all 3 staged channels).
  float A[8];
  {
    float Rv[8], Gv[8], Bv[8];
    const float* rp0 = lds + r * LDSS + blk * 8;
    load8_lds(rp0, Rv);
    load8_lds(rp0 + CSTR, Gv);
    load8_lds(rp0 + 2 * CSTR, Bv);
    if (c == 0) {
#pragma unroll
      for (int i = 0; i < 8; ++i)
        A[i] = fmaf(0.299f, Rv[i], fmaf(0.587f, Gv[i], 0.114f * Bv[i]));
    } else if (c == 1) {
#pragma unroll
      for (int i = 0; i < 8; ++i)
        A[i] = fmaf(-0.168736f, Rv[i], fmaf(-0.331264f, Gv[i], fmaf(0.5f, Bv[i], 0.5f)));
    } else {
#pragma unroll
      for (int i = 0; i < 8; ++i)
        A[i] = fmaf(0.5f, Rv[i], fmaf(-0.418688f, Gv[i], fmaf(-0.081312f, Bv[i], 0.5f)));
    }
  }
  __syncthreads();  // Bar2: cross-wave reads done before transpose scratch reuse

  // Per-wave single-channel pipeline (verified math, unchanged from baseline).
  float T[8];
  float* tp = lds + (c * 8 + blk) * LDSS;
  mul8<true>(A, T);    // T = X*D, row r
  transpose1(T, tp, r);
  mul8<false>(T, A);   // A = coef column r

  quant8(A, qcol, rqcol);

  mul8<true>(A, T);
  transpose1(T, tp, r);
  mul8<false>(T, A);   // A = rec row r of own channel

  // Stage reconstructed YCbCr (row layout), then own-output-channel color-back.
  store8_lds(sp, A);
  __syncthreads();  // Bar3

  {
    float Yv[8], Cbv[8], Crv[8];
    const float* rp0 = lds + r * LDSS + blk * 8;
    load8_lds(rp0, Yv);
    load8_lds(rp0 + CSTR, Cbv);
    load8_lds(rp0 + 2 * CSTR, Crv);
    float O[8];
    if (c == 0) {
#pragma unroll
      for (int i = 0; i < 8; ++i) O[i] = fmaf(1.402f, Crv[i], Yv[i] - 0.701f);
    } else if (c == 1) {
#pragma unroll
      for (int i = 0; i < 8; ++i)
        O[i] = fmaf(-0.344136f, Cbv[i], fmaf(-0.714136f, Crv[i], Yv[i] + 0.529136f));
    } else {
#pragma unroll
      for (int i = 0; i < 8; ++i) O[i] = fmaf(1.772f, Cbv[i], Yv[i] - 0.886f);
    }
#pragma unroll
    for (int i = 0; i < 8; ++i) O[i] = fminf(fmaxf(O[i], 0.0f), 1.0f);
    store8(out + poff, O);
  }
}

}  // namespace

extern "C" void kernel_launch(void* const* d_in, const int* in_sizes, int n_in,
                              void* d_out, int out_size, void* d_ws, size_t ws_size,
                              hipStream_t stream) {
  const float* img = (const float*)d_in[0];
  const float* qy = (const float*)d_in[1];
  const float* qc = (const float*)d_in[2];
  float* out = (float*)d_out;
  // 8 batches * 64 block-rows * 8 strips = 4096 workgroups of 3 channel-waves
  jpeg_kernel<<<dim3(4096), dim3(192), 0, stream>>>(img, qy, qc, out);
}